// Round 5
// baseline (837.985 us; speedup 1.0000x reference)
//
#include <hip/hip_runtime.h>
#include <hip/hip_bf16.h>

// Shapes (fixed): B=16, S=1024, P=32, G=64 -> L=2048, E=512, HD=256
// SCALE = 0.0625, LAMBDA_INIT = 0.2, EPS = 1e-5
// Round 10: fixes R9's K-split partial pointer bug (ks=1 partial was written at
// o2d + OUT0_ELEMS == rmsb region, while rmsnorm read the real o2dB -> poison).
// dv_wide now takes explicit o2dA/o2dB pointers. R9 design retained:
// (1) K-split x2 -> grid 1024 (4 blocks/CU), fp32 partials summed in rmsnorm.
// (2) P0/P1 register prefetch (T14 issue-early).
// (3) both-sides XOR swizzle on A/B LDS tiles (B via pre-swizzled global src).
// flags[0]: 1 = fp32 tensors (confirmed R3), 0 = bf16.

typedef short short8 __attribute__((ext_vector_type(8)));
typedef __bf16 bf16x8 __attribute__((ext_vector_type(8)));
typedef float f32x4 __attribute__((ext_vector_type(4)));

#define LDS_BYTES 16384
#define OUT0_ELEMS 8388608L

__global__ void probe_kernel(const void* gamma, const void* mask, int* flags)
{
    if (threadIdx.x == 0) {
        unsigned g = *(const unsigned*)gamma;
        flags[0] = (g == 0x3F800000u) ? 1 : 0;
        flags[1] = 0;
    }
    __syncthreads();
    const unsigned* mi = (const unsigned*)mask;
    int bad = 0;
    for (int i = threadIdx.x; i < 4096; i += blockDim.x)
        if (mi[i] > 1u) bad = 1;
    if (bad) atomicOr(&flags[1], 1);
}

__global__ void convert_mask(const void* __restrict__ mask, int* __restrict__ mi,
                             const int* __restrict__ flags)
{
    int i = blockIdx.x * 256 + threadIdx.x;   // 16384 total
    if (flags[1]) mi[i] = ((const unsigned char*)mask)[i] ? 1 : 0;
    else          mi[i] = ((const int*)mask)[i] ? 1 : 0;
}

__device__ __forceinline__ float read_elem(const void* p, int i, int isf32)
{
    return isf32 ? ((const float*)p)[i]
                 : __bfloat162float(((const __hip_bfloat16*)p)[i]);
}

__global__ void convert_gamma(const void* __restrict__ gamma, float* __restrict__ g,
                              const int* __restrict__ flags)
{
    int i = blockIdx.x * 256 + threadIdx.x;  // 512 total
    g[i] = read_elem(gamma, i, flags[0]);
}

__global__ void transpose_w(const void* __restrict__ Wq, const void* __restrict__ Wk,
                            const void* __restrict__ Wv, const void* __restrict__ Wo,
                            __hip_bfloat16* __restrict__ dst, const int* __restrict__ flags)
{
    int which = blockIdx.y;
    const void* s = (which == 0) ? Wq : (which == 1) ? Wk : (which == 2) ? Wv : Wo;
    __hip_bfloat16* d = dst + (long)which * 262144;
    int idx = blockIdx.x * 256 + threadIdx.x;  // 0..262143
    int k = idx >> 9, n = idx & 511;
    d[n * 512 + k] = __float2bfloat16(read_elem(s, idx, flags[0]));
}

__global__ void lam_kernel(const void* __restrict__ lq1, const void* __restrict__ lk1,
                           const void* __restrict__ lq2, const void* __restrict__ lk2,
                           float* __restrict__ lamp, const int* __restrict__ flags)
{
    int t = threadIdx.x; // 64
    int f = flags[0];
    float s1 = 0.0f, s2 = 0.0f;
#pragma unroll
    for (int j = 0; j < 4; ++j) {
        int idx = t * 4 + j;
        s1 += read_elem(lq1, idx, f) * read_elem(lk1, idx, f);
        s2 += read_elem(lq2, idx, f) * read_elem(lk2, idx, f);
    }
#pragma unroll
    for (int off = 1; off < 64; off <<= 1) {
        s1 += __shfl_xor(s1, off);
        s2 += __shfl_xor(s2, off);
    }
    if (t == 0) *lamp = __expf(s1) - __expf(s2) + 0.2f;
}

__global__ void zero_lst(float* __restrict__ lst)
{
    lst[blockIdx.x * 256 + threadIdx.x] = 0.0f;   // 32768 floats
}

// ---- stage 128x32 A-slice + 128x32 B-slice into LDS ----
__device__ __forceinline__ void stage_u(const void* A, long aoff, int lda, int af32,
                                        const __hip_bfloat16* B, int ldb,
                                        int kt, char* smem, int tid)
{
    if (af32) {
#pragma unroll
        for (int j = 0; j < 2; ++j) {
            int chunk = j * 256 + tid;
            const float* g = (const float*)A + aoff + (long)(chunk >> 2) * lda + kt + (chunk & 3) * 8;
            f32x4 x0 = *(const f32x4*)g;
            f32x4 x1 = *(const f32x4*)(g + 4);
            __hip_bfloat16 tmp[8];
#pragma unroll
            for (int t = 0; t < 4; ++t) tmp[t] = __float2bfloat16(x0[t]);
#pragma unroll
            for (int t = 0; t < 4; ++t) tmp[4 + t] = __float2bfloat16(x1[t]);
            *(short8*)(smem + chunk * 16) = *(const short8*)tmp;
        }
    } else {
#pragma unroll
        for (int j = 0; j < 2; ++j) {
            int chunk = j * 256 + tid;
            const __hip_bfloat16* g = (const __hip_bfloat16*)A + aoff
                                    + (long)(chunk >> 2) * lda + kt + (chunk & 3) * 8;
            __builtin_amdgcn_global_load_lds(
                (__attribute__((address_space(1))) void*)g,
                (__attribute__((address_space(3))) void*)(smem + chunk * 16), 16, 0, 0);
        }
    }
#pragma unroll
    for (int j = 0; j < 2; ++j) {
        int chunk = j * 256 + tid;
        const __hip_bfloat16* g = B + (long)(chunk >> 2) * ldb + kt + (chunk & 3) * 8;
        __builtin_amdgcn_global_load_lds(
            (__attribute__((address_space(1))) void*)g,
            (__attribute__((address_space(3))) void*)(smem + 8192 + chunk * 16), 16, 0, 0);
    }
}

__device__ __forceinline__ void mfma_block(char* smem, int tid, f32x4 (&acc)[4][4])
{
    const int lane = tid & 63, wid = tid >> 6;
    const int wm = wid >> 1, wn = wid & 1;
    const int lm = lane & 15, lq = lane >> 4;
    short8 a[4], b[4];
#pragma unroll
    for (int i = 0; i < 4; ++i)
        a[i] = *(const short8*)(smem + (wm * 64 + i * 16 + lm) * 64 + lq * 16);
#pragma unroll
    for (int i = 0; i < 4; ++i)
        b[i] = *(const short8*)(smem + 8192 + (wn * 64 + i * 16 + lm) * 64 + lq * 16);
#pragma unroll
    for (int i = 0; i < 4; ++i)
#pragma unroll
        for (int j = 0; j < 4; ++j)
            acc[i][j] = __builtin_amdgcn_mfma_f32_16x16x32_bf16(
                __builtin_bit_cast(bf16x8, a[i]),
                __builtin_bit_cast(bf16x8, b[j]),
                acc[i][j], 0, 0, 0);
}

__device__ __forceinline__ void zero_acc(f32x4 (&acc)[4][4])
{
#pragma unroll
    for (int i = 0; i < 4; ++i)
#pragma unroll
        for (int j = 0; j < 4; ++j)
#pragma unroll
            for (int r = 0; r < 4; ++r) acc[i][j][r] = 0.0f;
}

__device__ __forceinline__ void tile_gemm_u(const void* A, long aoff, int lda, int af32,
                                            const __hip_bfloat16* B, int ldb, int K,
                                            char* smem, int tid, f32x4 (&acc)[4][4])
{
    zero_acc(acc);
    for (int kt = 0; kt < K; kt += 32) {
        __syncthreads();
        stage_u(A, aoff, lda, af32, B, ldb, kt, smem, tid);
        __syncthreads();
        mfma_block(smem, tid, acc);
    }
}

// MODE 0: C bf16 scaled   MODE 1: Vt store   MODE 2: C fp32   MODE 3: d_out per flag
// AF: 0 = A bf16, 1 = A dtype per flags[0].
template <int MODE, int AF>
__launch_bounds__(256, 4)
__global__ void gemm_u(const void* __restrict__ A,
                       const __hip_bfloat16* __restrict__ B,
                       void* __restrict__ C,
                       int K, int lda, int ldb, int ldc,
                       long sA, long sB, long sC, float scale,
                       const int* __restrict__ flags)
{
    __shared__ __align__(16) char smem[LDS_BYTES];
    const int tid = threadIdx.x;
    const int bn = blockIdx.x, bm = blockIdx.y, bz = blockIdx.z;
    const int af32 = AF ? flags[0] : 0;
    const long aoff = (long)bz * sA + (long)bm * 128 * lda;
    const __hip_bfloat16* Bb = B + (long)bz * sB + (long)bn * 128 * ldb;

    f32x4 acc[4][4];
    tile_gemm_u(A, aoff, lda, af32, Bb, ldb, K, smem, tid, acc);

    const int f32o = (MODE == 3) ? flags[0] : 0;
    const int lane = tid & 63, wid = tid >> 6;
    const int wm = wid >> 1, wn = wid & 1;
    const int lm = lane & 15, lq = lane >> 4;
#pragma unroll
    for (int im = 0; im < 4; ++im)
#pragma unroll
        for (int in = 0; in < 4; ++in)
#pragma unroll
            for (int r = 0; r < 4; ++r) {
                int row = bm * 128 + wm * 64 + im * 16 + lq * 4 + r;
                int col = bn * 128 + wn * 64 + in * 16 + lm;
                float v = acc[im][in][r] * scale;
                if (MODE == 0) {
                    ((__hip_bfloat16*)C)[bz * sC + (long)row * ldc + col] = __float2bfloat16(v);
                } else if (MODE == 2) {
                    ((float*)C)[bz * sC + (long)row * ldc + col] = v;
                } else if (MODE == 3) {
                    long idx = bz * sC + (long)row * ldc + col;
                    if (f32o) ((float*)C)[idx] = v;
                    else      ((__hip_bfloat16*)C)[idx] = __float2bfloat16(v);
                } else {
                    int bb = row >> 11, l = row & 2047;
                    ((__hip_bfloat16*)C)[((long)bb * 512 + col) * 2048 + l] = __float2bfloat16(v);
                }
            }
}

// ---- fused score pass: P = exp(masked QK^T) bf16 + row-sum accumulation ----
__device__ __forceinline__ void score_epilogue(
    f32x4 (&acc)[4][4], char* smem, int tid,
    int nt, int st, int b, int bl, const int* __restrict__ mask,
    float* __restrict__ lstats, __hip_bfloat16* __restrict__ P, int h)
{
    const int lane = tid & 63, wid = tid >> 6;
    const int wm = wid >> 1, wn = wid & 1;
    const int lm = lane & 15, lq = lane >> 4;
    float esum[4][4];
#pragma unroll
    for (int im = 0; im < 4; ++im)
#pragma unroll
        for (int r = 0; r < 4; ++r) {
            int rl = wm * 64 + im * 16 + lq * 4 + r;
            int s  = st * 128 + rl;
            int mv = mask[b * 1024 + s];
            float es = 0.0f;
#pragma unroll
            for (int in = 0; in < 4; ++in) {
                int col = nt * 128 + wn * 64 + in * 16 + lm;
                float sc = mv ? acc[im][in][r] : 0.0f;
                float e  = __expf(sc);
                P[((long)bl * 1024 + s) * 2048 + col] = __float2bfloat16(e);
                float t = e;
                t += __shfl_xor(t, 1);
                t += __shfl_xor(t, 2);
                t += __shfl_xor(t, 4);
                t += __shfl_xor(t, 8);
                es += t;
            }
            esum[im][r] = es;
        }
    __syncthreads();
    float* red = (float*)smem;
    if (lm == 0) {
#pragma unroll
        for (int im = 0; im < 4; ++im)
#pragma unroll
            for (int r = 0; r < 4; ++r)
                red[wn * 128 + wm * 64 + im * 16 + lq * 4 + r] = esum[im][r];
    }
    __syncthreads();
    if (tid < 128)
        atomicAdd(&lstats[((long)(b * 2 + h)) * 1024 + st * 128 + tid],
                  red[tid] + red[128 + tid]);
}

__launch_bounds__(256, 3)
__global__ void score_kernel(const __hip_bfloat16* __restrict__ Q,
                             const __hip_bfloat16* __restrict__ Km,
                             const int* __restrict__ mask,
                             float* __restrict__ lstats,
                             __hip_bfloat16* __restrict__ P0,
                             __hip_bfloat16* __restrict__ P1,
                             int bbase)
{
    __shared__ __align__(16) char smem[LDS_BYTES];
    const int tid = threadIdx.x;
    const int nt = blockIdx.x, st = blockIdx.y, bl = blockIdx.z;
    const int b = bl + bbase;
    const long A0 = ((long)b * 1024 + st * 128) * 512;
    const __hip_bfloat16* B0 = Km + ((long)b * 2048 + nt * 128) * 512;

    f32x4 acc[4][4];
    tile_gemm_u(Q, A0, 512, 0, B0, 512, 256, smem, tid, acc);            // head 0
    score_epilogue(acc, smem, tid, nt, st, b, bl, mask, lstats, P0, 0);
    tile_gemm_u(Q, A0 + 256, 512, 0, B0 + 256, 512, 256, smem, tid, acc); // head 1
    score_epilogue(acc, smem, tid, nt, st, b, bl, mask, lstats, P1, 1);
}

// dv GEMM, wide-N + K-split: block = 32 rows x N=512 x K-half (1024).
// P0/P1 read exactly once. A-staging fuses diff = P0*i0 - lam*P1*i1 with
// register prefetch of the next k-step. A/B LDS tiles XOR-swizzled (B via
// pre-swizzled global source, rule #21). Grid (32 bm, 16 b, 2 ks);
// ks=0 -> o2dA partial, ks=1 -> o2dB partial; rmsnorm sums the two.
__launch_bounds__(256, 4)
__global__ void dv_wide(const __hip_bfloat16* __restrict__ P0,
                        const __hip_bfloat16* __restrict__ P1,
                        const __hip_bfloat16* __restrict__ Vt,
                        const float* __restrict__ lst,
                        const float* __restrict__ lamp,
                        float* __restrict__ o2dA,
                        float* __restrict__ o2dB,
                        void* __restrict__ dout,
                        const int* __restrict__ flags)
{
    __shared__ __align__(16) char smem[36864];   // A 32x32 bf16 (2KB pad 4KB) + B 512x32 bf16 (32KB)
    const int tid = threadIdx.x;
    const int bm = blockIdx.x, b = blockIdx.y, ks = blockIdx.z;
    const int k0 = ks * 1024, kend = k0 + 1024;
    const float lam = *lamp;

    const int arow = (tid >> 2) & 31;     // A role: threads 0..127 -> rows 0..31
    const int ac   = tid & 3;             // A col-block (8 bf16 each)
    const int srow = bm * 32 + arow;
    float i0 = 0.0f, i1 = 0.0f;
    if (tid < 128) {
        i0 = 1.0f / lst[((long)(b * 2)) * 1024 + srow];
        i1 = lam  / lst[((long)(b * 2 + 1)) * 1024 + srow];
    }
    const __hip_bfloat16* Bb = Vt + (long)b * (512L * 2048);
    const int f32o = flags[0];
    float* doutF = (float*)dout + OUT0_ELEMS;
    __hip_bfloat16* doutH = (__hip_bfloat16*)dout + OUT0_ELEMS;
    const long arowoff = ((long)b * 1024 + srow) * 2048;

    f32x4 acc[2][8];
#pragma unroll
    for (int im = 0; im < 2; ++im)
#pragma unroll
        for (int in = 0; in < 8; ++in)
#pragma unroll
            for (int r = 0; r < 4; ++r) acc[im][in][r] = 0.0f;

    const int lane = tid & 63, wid = tid >> 6;
    const int lm = lane & 15, lq = lane >> 4;

    union U8 { short8 v; __hip_bfloat16 h[8]; };
    U8 c0, c1, n0, n1;
    if (tid < 128) {
        c0.v = *(const short8*)(P0 + arowoff + k0 + ac * 8);
        c1.v = *(const short8*)(P1 + arowoff + k0 + ac * 8);
    }

    for (int kt = k0; kt < kend; kt += 32) {
        __syncthreads();
        // B stage: pre-swizzled global source so swizzled LDS reads are conflict-reduced
#pragma unroll
        for (int j = 0; j < 8; ++j) {
            int chunk = j * 256 + tid;                       // n = chunk>>2, c = chunk&3
            int n = chunk >> 2, c = chunk & 3;
            int csrc = c ^ (n & 3);
            const __hip_bfloat16* g = Bb + (long)n * 2048 + kt + csrc * 8;
            __builtin_amdgcn_global_load_lds(
                (__attribute__((address_space(1))) void*)g,
                (__attribute__((address_space(3))) void*)(smem + 4096 + chunk * 16), 16, 0, 0);
        }
        // A: fused diff from prefetched regs, swizzled LDS write
        float d[8];
        U8 ta;
        if (tid < 128) {
#pragma unroll
            for (int t = 0; t < 8; ++t)
                d[t] = __bfloat162float(c0.h[t]) * i0 - __bfloat162float(c1.h[t]) * i1;
#pragma unroll
            for (int t = 0; t < 8; ++t) ta.h[t] = __float2bfloat16(d[t]);
            *(short8*)(smem + arow * 64 + (ac ^ (arow & 3)) * 16) = ta.v;
            // prefetch next k-step (latency drains with the B gload_lds wait below)
            if (kt + 32 < kend) {
                n0.v = *(const short8*)(P0 + arowoff + kt + 32 + ac * 8);
                n1.v = *(const short8*)(P1 + arowoff + kt + 32 + ac * 8);
            }
        }
        __syncthreads();
        // d_out diff store (overlaps MFMA below)
        if (tid < 128) {
            long g = arowoff + kt + ac * 8;
            if (f32o) {
                f32x4 v0, v1;
#pragma unroll
                for (int t = 0; t < 4; ++t) { v0[t] = d[t]; v1[t] = d[4 + t]; }
                *(f32x4*)(doutF + g)     = v0;
                *(f32x4*)(doutF + g + 4) = v1;
            } else {
                *(short8*)(doutH + g) = ta.v;
            }
            c0 = n0; c1 = n1;
        }
        short8 af[2], bf[8];
#pragma unroll
        for (int im = 0; im < 2; ++im) {
            int row = im * 16 + lm;
            af[im] = *(const short8*)(smem + row * 64 + (lq ^ (row & 3)) * 16);
        }
#pragma unroll
        for (int in = 0; in < 8; ++in) {
            int n = wid * 128 + in * 16 + lm;
            bf[in] = *(const short8*)(smem + 4096 + n * 64 + (lq ^ (n & 3)) * 16);
        }
#pragma unroll
        for (int im = 0; im < 2; ++im)
#pragma unroll
            for (int in = 0; in < 8; ++in)
                acc[im][in] = __builtin_amdgcn_mfma_f32_16x16x32_bf16(
                    __builtin_bit_cast(bf16x8, af[im]),
                    __builtin_bit_cast(bf16x8, bf[in]),
                    acc[im][in], 0, 0, 0);
    }

    float* opart = ks ? o2dB : o2dA;
#pragma unroll
    for (int im = 0; im < 2; ++im)
#pragma unroll
        for (int in = 0; in < 8; ++in)
#pragma unroll
            for (int r = 0; r < 4; ++r) {
                int row = bm * 32 + im * 16 + lq * 4 + r;
                int col = wid * 128 + in * 16 + lm;
                opart[((long)b * 1024 + row) * 512 + col] = acc[im][in][r];
            }
}

// bigws fallback: dv GEMM with fused normalization, 128x128 tiles (x4 A re-read)
__launch_bounds__(256, 3)
__global__ void dv_fused(const __hip_bfloat16* __restrict__ P0,
                         const __hip_bfloat16* __restrict__ P1,
                         const __hip_bfloat16* __restrict__ Vt,
                         const float* __restrict__ lst,
                         const float* __restrict__ lamp,
                         float* __restrict__ o2d,
                         void* __restrict__ dout,
                         int bbase, const int* __restrict__ flags)
{
    __shared__ __align__(16) char smem[LDS_BYTES];
    const int tid = threadIdx.x;
    const int bn = blockIdx.x, bm = blockIdx.y, bz = blockIdx.z;
    const int b = bz + bbase;
    const float lam = *lamp;

    int srow[2]; float i0[2], i1[2];
#pragma unroll
    for (int j = 0; j < 2; ++j) {
        srow[j] = bm * 128 + j * 64 + (tid >> 2);
        i0[j] = 1.0f / lst[((long)(b * 2)) * 1024 + srow[j]];
        i1[j] = lam  / lst[((long)(b * 2 + 1)) * 1024 + srow[j]];
    }

    const __hip_bfloat16* Bb = Vt + (long)b * (512L * 2048) + (long)bn * 128 * 2048;
    const int f32o = flags[0];
    float* doutF = (float*)dout + OUT0_ELEMS;
    __hip_bfloat16* doutH = (__hip_bfloat16*)dout + OUT0_ELEMS;

    f32x4 acc[4][4];
    zero_acc(acc);

    for (int kt = 0; kt < 2048; kt += 32) {
        __syncthreads();
#pragma unroll
        for (int j = 0; j < 2; ++j) {
            int chunk = j * 256 + tid;
            int kc = kt + (chunk & 3) * 8;
            long off = ((long)bz * 1024 + srow[j]) * 2048 + kc;
            union { short8 v; __hip_bfloat16 h[8]; } u0, u1;
            u0.v = *(const short8*)(P0 + off);
            u1.v = *(const short8*)(P1 + off);
            float d[8];
#pragma unroll
            for (int t = 0; t < 8; ++t)
                d[t] = __bfloat162float(u0.h[t]) * i0[j]
                     - __bfloat162float(u1.h[t]) * i1[j];
            __hip_bfloat16 tmp[8];
#pragma unroll
            for (int t = 0; t < 8; ++t) tmp[t] = __float2bfloat16(d[t]);
            *(short8*)(smem + chunk * 16) = *(const short8*)tmp;
            if (bn == 0) {
                long g = ((long)b * 1024 + srow[j]) * 2048 + kc;
                if (f32o) {
                    f32x4 v0, v1;
#pragma unroll
                    for (int t = 0; t < 4; ++t) { v0[t] = d[t]; v1[t] = d[4 + t]; }
                    *(f32x4*)(doutF + g)     = v0;
                    *(f32x4*)(doutF + g + 4) = v1;
                } else {
                    *(short8*)(doutH + g) = *(const short8*)tmp;
                }
            }
        }
#pragma unroll
        for (int j = 0; j < 2; ++j) {
            int chunk = j * 256 + tid;
            const __hip_bfloat16* g = Bb + (long)(chunk >> 2) * 2048 + kt + (chunk & 3) * 8;
            __builtin_amdgcn_global_load_lds(
                (__attribute__((address_space(1))) void*)g,
                (__attribute__((address_space(3))) void*)(smem + 8192 + chunk * 16), 16, 0, 0);
        }
        __syncthreads();
        mfma_block(smem, tid, acc);
    }

    const int lane = tid & 63, wid = tid >> 6;
    const int wm = wid >> 1, wn = wid & 1;
    const int lm = lane & 15, lq = lane >> 4;
#pragma unroll
    for (int im = 0; im < 4; ++im)
#pragma unroll
        for (int in = 0; in < 4; ++in)
#pragma unroll
            for (int r = 0; r < 4; ++r) {
                int row = bm * 128 + wm * 64 + im * 16 + lq * 4 + r;
                int col = bn * 128 + wn * 64 + in * 16 + lm;
                o2d[((long)b * 1024 + row) * 512 + col] = acc[im][in][r];
            }
}

// smallws fallback: diff = P0/l0 - lam*P1/l1 -> d_out + bf16 in-place over P0
__global__ void finalize_kernel(__hip_bfloat16* P0,
                                const __hip_bfloat16* __restrict__ P1,
                                const float* __restrict__ lstats,
                                const float* __restrict__ lamp,
                                void* dout, int bbase,
                                const int* __restrict__ flags)
{
    const long row = blockIdx.x;               // bl*1024 + s, grid.x = 8192
    const int bl = (int)(row >> 10), s = (int)(row & 1023);
    const int b  = bl + bbase;
    const int tid = threadIdx.x;               // 256, 8 cols each
    const float lam = *lamp;
    const float i0 = 1.0f / lstats[((long)(b * 2)) * 1024 + s];
    const float i1 = lam  / lstats[((long)(b * 2 + 1)) * 1024 + s];
    const long lbase = row * 2048 + (long)tid * 8;

    union { short8 v; __hip_bfloat16 h[8]; } u0, u1, ub;
    u0.v = *(const short8*)(P0 + lbase);
    u1.v = *(const short8*)(P1 + lbase);
    float d[8];
#pragma unroll
    for (int j = 0; j < 8; ++j)
        d[j] = __bfloat162float(u0.h[j]) * i0 - __bfloat162float(u1.h[j]) * i1;

    const long gidx = ((long)b * 1024 + s) * 2048 + (long)tid * 8;
    if (flags[0]) {
        float* outF = (float*)dout + OUT0_ELEMS;
        f32x4 v0, v1;
#pragma unroll
        for (int j = 0; j < 4; ++j) { v0[j] = d[j]; v1[j] = d[4 + j]; }
        *(f32x4*)(outF + gidx)     = v0;
        *(f32x4*)(outF + gidx + 4) = v1;
    } else {
        __hip_bfloat16* outH = (__hip_bfloat16*)dout + OUT0_ELEMS;
        union { short8 v; __hip_bfloat16 h[8]; } uo;
#pragma unroll
        for (int j = 0; j < 8; ++j) uo.h[j] = __float2bfloat16(d[j]);
        *(short8*)(outH + gidx) = uo.v;
    }
#pragma unroll
    for (int j = 0; j < 8; ++j) ub.h[j] = __float2bfloat16(d[j]);
    *(short8*)(P0 + lbase) = ub.v;
}

// X1 == nullptr -> single input; else sums the two K-split partials.
__global__ void rmsnorm_kernel(const float* __restrict__ X0,
                               const float* __restrict__ X1,
                               const float* __restrict__ gamma,
                               __hip_bfloat16* __restrict__ Y)
{
    long row = blockIdx.x;
    int lane = threadIdx.x; // 64
    const float* x = X0 + row * 512 + lane * 8;
    f32x4 v0 = *(const f32x4*)x;
    f32x4 v1 = *(const f32x4*)(x + 4);
    if (X1) {
        const float* y = X1 + row * 512 + lane * 8;
        f32x4 w0 = *(const f32x4*)y;
        f32x4 w1 = *(const f32x4*)(y + 4);
#pragma unroll
        for (int j = 0; j < 4; ++j) { v0[j] += w0[j]; v1[j] += w1[j]; }
    }
    float ss = v0[0] * v0[0] + v0[1] * v0[1] + v0[2] * v0[2] + v0[3] * v0[3]
             + v1[0] * v1[0] + v1[1] * v1[1] + v1[2] * v1[2] + v1[3] * v1[3];
#pragma unroll
    for (int off = 1; off < 64; off <<= 1) ss += __shfl_xor(ss, off);
    float rinv = rsqrtf(ss * (1.0f / 512.0f) + 1e-5f) * 0.8f;
#pragma unroll
    for (int j = 0; j < 4; ++j)
        Y[row * 512 + lane * 8 + j] = __float2bfloat16(v0[j] * rinv * gamma[lane * 8 + j]);
#pragma unroll
    for (int j = 0; j < 4; ++j)
        Y[row * 512 + lane * 8 + 4 + j] = __float2bfloat16(v1[j] * rinv * gamma[lane * 8 + 4 + j]);
}

extern "C" void kernel_launch(void* const* d_in, const int* in_sizes, int n_in,
                              void* d_out, int out_size, void* d_ws, size_t ws_size,
                              hipStream_t stream)
{
    const void* query = d_in[0];
    const void* key2d = d_in[1];
    const void* maskp = d_in[2];
    const void* Wq    = d_in[3];
    const void* Wk    = d_in[4];
    const void* Wv    = d_in[5];
    const void* Wo    = d_in[6];
    const void* lq1   = d_in[7];
    const void* lk1   = d_in[8];
    const void* lq2   = d_in[9];
    const void* lk2   = d_in[10];
    const void* gamma = d_in[11];

    // workspace layout (base ~136.6 MB; P buffers + o2d partial after, tiered)
    char* w = (char*)d_ws;
    __hip_bfloat16* WT    = (__hip_bfloat16*)(w);
    __hip_bfloat16* WqT   = WT;
    __hip_bfloat16* WkT   = WT + 262144;
    __hip_bfloat16* WvT   = WT + 524288;
    __hip_bfloat16* WoT   = WT + 786432;
    float*          lamp  = (float*)(w + 2097152);
    int*            flags = (int*)(w + 2097216);
    float*          gammaF= (float*)(w + 2097280);
    int*            maskI = (int*)(w + 2162688);
    __hip_bfloat16* Qb    = (__hip_bfloat16*)(w + 2228224);
    __hip_bfloat16* Kb    = (__hip_bfloat16*)(w + 19005440);
    __hip_bfloat16* Vt    = (__hip_bfloat16*)(w + 52559872);
    float*          lst   = (float*)(w + 86114304);
    float*          o2d   = (float*)(w + 86245376);
    __hip_bfloat16* rmsb  = (__hip_bfloat16*)(w + 119799808);
    __hip_bfloat16* diffBF= (__hip_bfloat16*)(w + 136577024);
    float*          o2dB  = (float*)(w + 270794752);   // K-split partial #2 (33.5 MB)
    // smallws-only P1 scratch aliasing o2d upper + rmsb
    __hip_bfloat16* P1s   = (__hip_bfloat16*)(w + 103022592);

    const bool hugews = ws_size >= 304349184UL;  // +134MB P0/P1 +33.5MB o2dB
    const bool bigws  = ws_size >= 203685888UL;  // +67MB (P0/P1 halves)

    probe_kernel<<<1, 256, 0, stream>>>(gamma, maskp, flags);
    convert_mask<<<64, 256, 0, stream>>>(maskp, maskI, flags);
    convert_gamma<<<2, 256, 0, stream>>>(gamma, gammaF, flags);
    transpose_w<<<dim3(1024, 4, 1), 256, 0, stream>>>(Wq, Wk, Wv, Wo, WT, flags);
    lam_kernel<<<1, 64, 0, stream>>>(lq1, lk1, lq2, lk2, lamp, flags);
    zero_lst<<<128, 256, 0, stream>>>(lst);

    // Q = (query @ Wq) * SCALE
    gemm_u<0, 1><<<dim3(4, 128, 1), 256, 0, stream>>>(query, WqT, Qb,
        512, 512, 512, 512, 0, 0, 0, 0.0625f, flags);
    // K = key2d @ Wk
    gemm_u<0, 1><<<dim3(4, 256, 1), 256, 0, stream>>>(key2d, WkT, Kb,
        512, 512, 512, 512, 0, 0, 0, 1.0f, flags);
    // V^T per batch
    gemm_u<1, 1><<<dim3(4, 256, 1), 256, 0, stream>>>(key2d, WvT, Vt,
        512, 512, 512, 0, 0, 0, 0, 1.0f, flags);

    if (hugews) {
        // single pass: full P0 (67MB) + P1 (67MB); P read exactly once by dv_wide
        __hip_bfloat16* P0f = diffBF;
        __hip_bfloat16* P1f = diffBF + 33554432L;
        score_kernel<<<dim3(16, 8, 16), 256, 0, stream>>>(Qb, Kb, maskI, lst,
            P0f, P1f, 0);
        dv_wide<<<dim3(32, 16, 2), 256, 0, stream>>>(P0f, P1f, Vt, lst, lamp,
            o2d, o2dB, d_out, flags);
        rmsnorm_kernel<<<16384, 64, 0, stream>>>(o2d, o2dB, gammaF, rmsb);
    } else if (bigws) {
        // two half-batch passes: P0/P1 halves inside the 67MB diffBF region
        __hip_bfloat16* P0h = diffBF;
        __hip_bfloat16* P1h = diffBF + 16777216L;
        for (int h = 0; h < 2; ++h) {
            int bb = h * 8;
            score_kernel<<<dim3(16, 8, 8), 256, 0, stream>>>(Qb, Kb, maskI, lst,
                P0h, P1h, bb);
            dv_fused<<<dim3(4, 8, 8), 256, 0, stream>>>(P0h, P1h, Vt, lst, lamp,
                o2d, d_out, bb, flags);
        }
        rmsnorm_kernel<<<16384, 64, 0, stream>>>(o2d, nullptr, gammaF, rmsb);
    } else {
        // fallback: bf16 P0 scratch = d_out out0 region, P1 = aliased scratch,
        // finalize before dv (ordering keeps aliases safe)
        __hip_bfloat16* scratch = (__hip_bfloat16*)d_out;
        for (int h = 0; h < 2; ++h) {
            int bb = h * 8;
            score_kernel<<<dim3(16, 8, 8), 256, 0, stream>>>(Qb, Kb, maskI, lst,
                scratch, P1s, bb);
            finalize_kernel<<<8192, 256, 0, stream>>>(scratch, P1s, lst, lamp,
                d_out, bb, flags);
            gemm_u<2, 0><<<dim3(4, 8, 8), 256, 0, stream>>>(scratch,
                Vt + (long)bb * 512 * 2048, o2d + (long)bb * 1024 * 512,
                2048, 2048, 2048, 512, 1024L * 2048, 512L * 2048, 1024L * 512, 1.0f, flags);
        }
        rmsnorm_kernel<<<16384, 64, 0, stream>>>(o2d, nullptr, gammaF, rmsb);
    }

    // out = rms @ Wo -> d_out out0 region (overwrites any scratch)
    gemm_u<3, 0><<<dim3(4, 128, 1), 256, 0, stream>>>(rmsb, WoT, d_out,
        512, 512, 512, 512, 0, 0, 1024L * 512, 1.0f, flags);
}

// Round 6
// 632.721 us; speedup vs baseline: 1.3244x; 1.3244x over previous
//
#include <hip/hip_runtime.h>
#include <hip/hip_bf16.h>

// Shapes (fixed): B=16, S=1024, P=32, G=64 -> L=2048, E=512, HD=256
// SCALE = 0.0625, LAMBDA_INIT = 0.2, EPS = 1e-5
// Round 11: the R2-R5 "fuse normalization into dv GEMM" arc lost every round
// (R1 unfused: 646us; fused variants: 671-838us — x4 P re-reads, latency-bound
// skinny tiles, or Vt locality collapse). Reverted to R1's proven pipeline
// (score -> finalize -> clean 128x128 dv GEMM), but single-pass over all 16
// batches (ws ~640MB): one score launch (2048 blocks), one finalize (16384),
// one dv gemm (512, A+Vt+writes = 132MB < L3). Fewer launch tails.
// flags[0]: 1 = fp32 tensors (confirmed R3), 0 = bf16.

typedef short short8 __attribute__((ext_vector_type(8)));
typedef __bf16 bf16x8 __attribute__((ext_vector_type(8)));
typedef float f32x4 __attribute__((ext_vector_type(4)));

#define LDS_BYTES 16384
#define OUT0_ELEMS 8388608L

__global__ void probe_kernel(const void* gamma, const void* mask, int* flags)
{
    if (threadIdx.x == 0) {
        unsigned g = *(const unsigned*)gamma;
        flags[0] = (g == 0x3F800000u) ? 1 : 0;
        flags[1] = 0;
    }
    __syncthreads();
    const unsigned* mi = (const unsigned*)mask;
    int bad = 0;
    for (int i = threadIdx.x; i < 4096; i += blockDim.x)
        if (mi[i] > 1u) bad = 1;
    if (bad) atomicOr(&flags[1], 1);
}

__global__ void convert_mask(const void* __restrict__ mask, int* __restrict__ mi,
                             const int* __restrict__ flags)
{
    int i = blockIdx.x * 256 + threadIdx.x;   // 16384 total
    if (flags[1]) mi[i] = ((const unsigned char*)mask)[i] ? 1 : 0;
    else          mi[i] = ((const int*)mask)[i] ? 1 : 0;
}

__device__ __forceinline__ float read_elem(const void* p, int i, int isf32)
{
    return isf32 ? ((const float*)p)[i]
                 : __bfloat162float(((const __hip_bfloat16*)p)[i]);
}

__global__ void convert_gamma(const void* __restrict__ gamma, float* __restrict__ g,
                              const int* __restrict__ flags)
{
    int i = blockIdx.x * 256 + threadIdx.x;  // 512 total
    g[i] = read_elem(gamma, i, flags[0]);
}

__global__ void transpose_w(const void* __restrict__ Wq, const void* __restrict__ Wk,
                            const void* __restrict__ Wv, const void* __restrict__ Wo,
                            __hip_bfloat16* __restrict__ dst, const int* __restrict__ flags)
{
    int which = blockIdx.y;
    const void* s = (which == 0) ? Wq : (which == 1) ? Wk : (which == 2) ? Wv : Wo;
    __hip_bfloat16* d = dst + (long)which * 262144;
    int idx = blockIdx.x * 256 + threadIdx.x;  // 0..262143
    int k = idx >> 9, n = idx & 511;
    d[n * 512 + k] = __float2bfloat16(read_elem(s, idx, flags[0]));
}

__global__ void lam_kernel(const void* __restrict__ lq1, const void* __restrict__ lk1,
                           const void* __restrict__ lq2, const void* __restrict__ lk2,
                           float* __restrict__ lamp, const int* __restrict__ flags)
{
    int t = threadIdx.x; // 64
    int f = flags[0];
    float s1 = 0.0f, s2 = 0.0f;
#pragma unroll
    for (int j = 0; j < 4; ++j) {
        int idx = t * 4 + j;
        s1 += read_elem(lq1, idx, f) * read_elem(lk1, idx, f);
        s2 += read_elem(lq2, idx, f) * read_elem(lk2, idx, f);
    }
#pragma unroll
    for (int off = 1; off < 64; off <<= 1) {
        s1 += __shfl_xor(s1, off);
        s2 += __shfl_xor(s2, off);
    }
    if (t == 0) *lamp = __expf(s1) - __expf(s2) + 0.2f;
}

__global__ void zero_lst(float* __restrict__ lst)
{
    lst[blockIdx.x * 256 + threadIdx.x] = 0.0f;   // 32768 floats
}

// ---- stage 128x32 A-slice + 128x32 B-slice into LDS ----
__device__ __forceinline__ void stage_u(const void* A, long aoff, int lda, int af32,
                                        const __hip_bfloat16* B, int ldb,
                                        int kt, char* smem, int tid)
{
    if (af32) {
#pragma unroll
        for (int j = 0; j < 2; ++j) {
            int chunk = j * 256 + tid;
            const float* g = (const float*)A + aoff + (long)(chunk >> 2) * lda + kt + (chunk & 3) * 8;
            f32x4 x0 = *(const f32x4*)g;
            f32x4 x1 = *(const f32x4*)(g + 4);
            __hip_bfloat16 tmp[8];
#pragma unroll
            for (int t = 0; t < 4; ++t) tmp[t] = __float2bfloat16(x0[t]);
#pragma unroll
            for (int t = 0; t < 4; ++t) tmp[4 + t] = __float2bfloat16(x1[t]);
            *(short8*)(smem + chunk * 16) = *(const short8*)tmp;
        }
    } else {
#pragma unroll
        for (int j = 0; j < 2; ++j) {
            int chunk = j * 256 + tid;
            const __hip_bfloat16* g = (const __hip_bfloat16*)A + aoff
                                    + (long)(chunk >> 2) * lda + kt + (chunk & 3) * 8;
            __builtin_amdgcn_global_load_lds(
                (__attribute__((address_space(1))) void*)g,
                (__attribute__((address_space(3))) void*)(smem + chunk * 16), 16, 0, 0);
        }
    }
#pragma unroll
    for (int j = 0; j < 2; ++j) {
        int chunk = j * 256 + tid;
        const __hip_bfloat16* g = B + (long)(chunk >> 2) * ldb + kt + (chunk & 3) * 8;
        __builtin_amdgcn_global_load_lds(
            (__attribute__((address_space(1))) void*)g,
            (__attribute__((address_space(3))) void*)(smem + 8192 + chunk * 16), 16, 0, 0);
    }
}

__device__ __forceinline__ void mfma_block(char* smem, int tid, f32x4 (&acc)[4][4])
{
    const int lane = tid & 63, wid = tid >> 6;
    const int wm = wid >> 1, wn = wid & 1;
    const int lm = lane & 15, lq = lane >> 4;
    short8 a[4], b[4];
#pragma unroll
    for (int i = 0; i < 4; ++i)
        a[i] = *(const short8*)(smem + (wm * 64 + i * 16 + lm) * 64 + lq * 16);
#pragma unroll
    for (int i = 0; i < 4; ++i)
        b[i] = *(const short8*)(smem + 8192 + (wn * 64 + i * 16 + lm) * 64 + lq * 16);
#pragma unroll
    for (int i = 0; i < 4; ++i)
#pragma unroll
        for (int j = 0; j < 4; ++j)
            acc[i][j] = __builtin_amdgcn_mfma_f32_16x16x32_bf16(
                __builtin_bit_cast(bf16x8, a[i]),
                __builtin_bit_cast(bf16x8, b[j]),
                acc[i][j], 0, 0, 0);
}

__device__ __forceinline__ void zero_acc(f32x4 (&acc)[4][4])
{
#pragma unroll
    for (int i = 0; i < 4; ++i)
#pragma unroll
        for (int j = 0; j < 4; ++j)
#pragma unroll
            for (int r = 0; r < 4; ++r) acc[i][j][r] = 0.0f;
}

__device__ __forceinline__ void tile_gemm_u(const void* A, long aoff, int lda, int af32,
                                            const __hip_bfloat16* B, int ldb, int K,
                                            char* smem, int tid, f32x4 (&acc)[4][4])
{
    zero_acc(acc);
    for (int kt = 0; kt < K; kt += 32) {
        __syncthreads();
        stage_u(A, aoff, lda, af32, B, ldb, kt, smem, tid);
        __syncthreads();
        mfma_block(smem, tid, acc);
    }
}

// MODE 0: C bf16 scaled   MODE 1: Vt store   MODE 2: C fp32   MODE 3: d_out per flag
// AF: 0 = A bf16, 1 = A dtype per flags[0].
template <int MODE, int AF>
__launch_bounds__(256, 4)
__global__ void gemm_u(const void* __restrict__ A,
                       const __hip_bfloat16* __restrict__ B,
                       void* __restrict__ C,
                       int K, int lda, int ldb, int ldc,
                       long sA, long sB, long sC, float scale,
                       const int* __restrict__ flags)
{
    __shared__ __align__(16) char smem[LDS_BYTES];
    const int tid = threadIdx.x;
    const int bn = blockIdx.x, bm = blockIdx.y, bz = blockIdx.z;
    const int af32 = AF ? flags[0] : 0;
    const long aoff = (long)bz * sA + (long)bm * 128 * lda;
    const __hip_bfloat16* Bb = B + (long)bz * sB + (long)bn * 128 * ldb;

    f32x4 acc[4][4];
    tile_gemm_u(A, aoff, lda, af32, Bb, ldb, K, smem, tid, acc);

    const int f32o = (MODE == 3) ? flags[0] : 0;
    const int lane = tid & 63, wid = tid >> 6;
    const int wm = wid >> 1, wn = wid & 1;
    const int lm = lane & 15, lq = lane >> 4;
#pragma unroll
    for (int im = 0; im < 4; ++im)
#pragma unroll
        for (int in = 0; in < 4; ++in)
#pragma unroll
            for (int r = 0; r < 4; ++r) {
                int row = bm * 128 + wm * 64 + im * 16 + lq * 4 + r;
                int col = bn * 128 + wn * 64 + in * 16 + lm;
                float v = acc[im][in][r] * scale;
                if (MODE == 0) {
                    ((__hip_bfloat16*)C)[bz * sC + (long)row * ldc + col] = __float2bfloat16(v);
                } else if (MODE == 2) {
                    ((float*)C)[bz * sC + (long)row * ldc + col] = v;
                } else if (MODE == 3) {
                    long idx = bz * sC + (long)row * ldc + col;
                    if (f32o) ((float*)C)[idx] = v;
                    else      ((__hip_bfloat16*)C)[idx] = __float2bfloat16(v);
                } else {
                    int bb = row >> 11, l = row & 2047;
                    ((__hip_bfloat16*)C)[((long)bb * 512 + col) * 2048 + l] = __float2bfloat16(v);
                }
            }
}

// ---- fused score pass: P = exp(masked QK^T) bf16 + row-sum accumulation ----
__device__ __forceinline__ void score_epilogue(
    f32x4 (&acc)[4][4], char* smem, int tid,
    int nt, int st, int b, int bl, const int* __restrict__ mask,
    float* __restrict__ lstats, __hip_bfloat16* __restrict__ P, int h)
{
    const int lane = tid & 63, wid = tid >> 6;
    const int wm = wid >> 1, wn = wid & 1;
    const int lm = lane & 15, lq = lane >> 4;
    float esum[4][4];
#pragma unroll
    for (int im = 0; im < 4; ++im)
#pragma unroll
        for (int r = 0; r < 4; ++r) {
            int rl = wm * 64 + im * 16 + lq * 4 + r;
            int s  = st * 128 + rl;
            int mv = mask[b * 1024 + s];
            float es = 0.0f;
#pragma unroll
            for (int in = 0; in < 4; ++in) {
                int col = nt * 128 + wn * 64 + in * 16 + lm;
                float sc = mv ? acc[im][in][r] : 0.0f;
                float e  = __expf(sc);
                P[((long)bl * 1024 + s) * 2048 + col] = __float2bfloat16(e);
                float t = e;
                t += __shfl_xor(t, 1);
                t += __shfl_xor(t, 2);
                t += __shfl_xor(t, 4);
                t += __shfl_xor(t, 8);
                es += t;
            }
            esum[im][r] = es;
        }
    __syncthreads();
    float* red = (float*)smem;
    if (lm == 0) {
#pragma unroll
        for (int im = 0; im < 4; ++im)
#pragma unroll
            for (int r = 0; r < 4; ++r)
                red[wn * 128 + wm * 64 + im * 16 + lq * 4 + r] = esum[im][r];
    }
    __syncthreads();
    if (tid < 128)
        atomicAdd(&lstats[((long)(b * 2 + h)) * 1024 + st * 128 + tid],
                  red[tid] + red[128 + tid]);
}

__launch_bounds__(256, 3)
__global__ void score_kernel(const __hip_bfloat16* __restrict__ Q,
                             const __hip_bfloat16* __restrict__ Km,
                             const int* __restrict__ mask,
                             float* __restrict__ lstats,
                             __hip_bfloat16* __restrict__ P0,
                             __hip_bfloat16* __restrict__ P1,
                             int bbase)
{
    __shared__ __align__(16) char smem[LDS_BYTES];
    const int tid = threadIdx.x;
    const int nt = blockIdx.x, st = blockIdx.y, bl = blockIdx.z;
    const int b = bl + bbase;
    const long A0 = ((long)b * 1024 + st * 128) * 512;
    const __hip_bfloat16* B0 = Km + ((long)b * 2048 + nt * 128) * 512;

    f32x4 acc[4][4];
    tile_gemm_u(Q, A0, 512, 0, B0, 512, 256, smem, tid, acc);            // head 0
    score_epilogue(acc, smem, tid, nt, st, b, bl, mask, lstats, P0, 0);
    tile_gemm_u(Q, A0 + 256, 512, 0, B0 + 256, 512, 256, smem, tid, acc); // head 1
    score_epilogue(acc, smem, tid, nt, st, b, bl, mask, lstats, P1, 1);
}

// diff = P0/l0 - lam*P1/l1 -> fp32 (or bf16) diff to d_out AND bf16 diff
// IN-PLACE over P0 (same thread reads then writes the same address -> safe).
// P0/P1 local-batch indexed; d_out diff region global-batch indexed.
__global__ void finalize_kernel(__hip_bfloat16* P0,
                                const __hip_bfloat16* __restrict__ P1,
                                const float* __restrict__ lstats,
                                const float* __restrict__ lamp,
                                void* dout, int bbase,
                                const int* __restrict__ flags)
{
    const long row = blockIdx.x;               // bl*1024 + s
    const int bl = (int)(row >> 10), s = (int)(row & 1023);
    const int b  = bl + bbase;
    const int tid = threadIdx.x;               // 256, 8 cols each
    const float lam = *lamp;
    const float i0 = 1.0f / lstats[((long)(b * 2)) * 1024 + s];
    const float i1 = lam  / lstats[((long)(b * 2 + 1)) * 1024 + s];
    const long lbase = row * 2048 + (long)tid * 8;

    union { short8 v; __hip_bfloat16 h[8]; } u0, u1, ub;
    u0.v = *(const short8*)(P0 + lbase);
    u1.v = *(const short8*)(P1 + lbase);
    float d[8];
#pragma unroll
    for (int j = 0; j < 8; ++j)
        d[j] = __bfloat162float(u0.h[j]) * i0 - __bfloat162float(u1.h[j]) * i1;

    const long gidx = ((long)b * 1024 + s) * 2048 + (long)tid * 8;
    if (flags[0]) {
        float* outF = (float*)dout + OUT0_ELEMS;
        f32x4 v0, v1;
#pragma unroll
        for (int j = 0; j < 4; ++j) { v0[j] = d[j]; v1[j] = d[4 + j]; }
        *(f32x4*)(outF + gidx)     = v0;
        *(f32x4*)(outF + gidx + 4) = v1;
    } else {
        __hip_bfloat16* outH = (__hip_bfloat16*)dout + OUT0_ELEMS;
        union { short8 v; __hip_bfloat16 h[8]; } uo;
#pragma unroll
        for (int j = 0; j < 8; ++j) uo.h[j] = __float2bfloat16(d[j]);
        *(short8*)(outH + gidx) = uo.v;
    }
#pragma unroll
    for (int j = 0; j < 8; ++j) ub.h[j] = __float2bfloat16(d[j]);
    *(short8*)(P0 + lbase) = ub.v;
}

__global__ void rmsnorm_kernel(const float* __restrict__ X,
                               const float* __restrict__ gamma,
                               __hip_bfloat16* __restrict__ Y)
{
    long row = blockIdx.x;
    int lane = threadIdx.x; // 64
    const float* x = X + row * 512 + lane * 8;
    f32x4 v0 = *(const f32x4*)x;
    f32x4 v1 = *(const f32x4*)(x + 4);
    float ss = v0[0] * v0[0] + v0[1] * v0[1] + v0[2] * v0[2] + v0[3] * v0[3]
             + v1[0] * v1[0] + v1[1] * v1[1] + v1[2] * v1[2] + v1[3] * v1[3];
#pragma unroll
    for (int off = 1; off < 64; off <<= 1) ss += __shfl_xor(ss, off);
    float rinv = rsqrtf(ss * (1.0f / 512.0f) + 1e-5f) * 0.8f;
#pragma unroll
    for (int j = 0; j < 4; ++j)
        Y[row * 512 + lane * 8 + j] = __float2bfloat16(v0[j] * rinv * gamma[lane * 8 + j]);
#pragma unroll
    for (int j = 0; j < 4; ++j)
        Y[row * 512 + lane * 8 + 4 + j] = __float2bfloat16(v1[j] * rinv * gamma[lane * 8 + 4 + j]);
}

extern "C" void kernel_launch(void* const* d_in, const int* in_sizes, int n_in,
                              void* d_out, int out_size, void* d_ws, size_t ws_size,
                              hipStream_t stream)
{
    const void* query = d_in[0];
    const void* key2d = d_in[1];
    const void* maskp = d_in[2];
    const void* Wq    = d_in[3];
    const void* Wk    = d_in[4];
    const void* Wv    = d_in[5];
    const void* Wo    = d_in[6];
    const void* lq1   = d_in[7];
    const void* lk1   = d_in[8];
    const void* lq2   = d_in[9];
    const void* lk2   = d_in[10];
    const void* gamma = d_in[11];

    // workspace layout (base ~136.6 MB; P buffers after, tiered by ws_size)
    char* w = (char*)d_ws;
    __hip_bfloat16* WT    = (__hip_bfloat16*)(w);
    __hip_bfloat16* WqT   = WT;
    __hip_bfloat16* WkT   = WT + 262144;
    __hip_bfloat16* WvT   = WT + 524288;
    __hip_bfloat16* WoT   = WT + 786432;
    float*          lamp  = (float*)(w + 2097152);
    int*            flags = (int*)(w + 2097216);
    float*          gammaF= (float*)(w + 2097280);
    int*            maskI = (int*)(w + 2162688);
    __hip_bfloat16* Qb    = (__hip_bfloat16*)(w + 2228224);
    __hip_bfloat16* Kb    = (__hip_bfloat16*)(w + 19005440);
    __hip_bfloat16* Vt    = (__hip_bfloat16*)(w + 52559872);
    float*          lst   = (float*)(w + 86114304);
    float*          o2d   = (float*)(w + 86245376);
    __hip_bfloat16* rmsb  = (__hip_bfloat16*)(w + 119799808);
    __hip_bfloat16* diffBF= (__hip_bfloat16*)(w + 136577024);
    // smallws-only P1 scratch aliasing o2d upper + rmsb (finalize ordering keeps safe)
    __hip_bfloat16* P1s   = (__hip_bfloat16*)(w + 103022592);

    const bool hugews = ws_size >= 270794752UL;  // +67MB P0 +67MB P1 (full batch)
    const bool bigws  = ws_size >= 203685888UL;  // +67MB (P0/P1 halves)

    probe_kernel<<<1, 256, 0, stream>>>(gamma, maskp, flags);
    convert_mask<<<64, 256, 0, stream>>>(maskp, maskI, flags);
    convert_gamma<<<2, 256, 0, stream>>>(gamma, gammaF, flags);
    transpose_w<<<dim3(1024, 4, 1), 256, 0, stream>>>(Wq, Wk, Wv, Wo, WT, flags);
    lam_kernel<<<1, 64, 0, stream>>>(lq1, lk1, lq2, lk2, lamp, flags);
    zero_lst<<<128, 256, 0, stream>>>(lst);

    // Q = (query @ Wq) * SCALE
    gemm_u<0, 1><<<dim3(4, 128, 1), 256, 0, stream>>>(query, WqT, Qb,
        512, 512, 512, 512, 0, 0, 0, 0.0625f, flags);
    // K = key2d @ Wk
    gemm_u<0, 1><<<dim3(4, 256, 1), 256, 0, stream>>>(key2d, WkT, Kb,
        512, 512, 512, 512, 0, 0, 0, 1.0f, flags);
    // V^T per batch
    gemm_u<1, 1><<<dim3(4, 256, 1), 256, 0, stream>>>(key2d, WvT, Vt,
        512, 512, 512, 0, 0, 0, 0, 1.0f, flags);

    if (hugews) {
        // single pass over all 16 batches: score -> finalize -> dv gemm
        __hip_bfloat16* P0f = diffBF;
        __hip_bfloat16* P1f = diffBF + 33554432L;
        score_kernel<<<dim3(16, 8, 16), 256, 0, stream>>>(Qb, Kb, maskI, lst,
            P0f, P1f, 0);
        finalize_kernel<<<16384, 256, 0, stream>>>(P0f, P1f, lst, lamp,
            d_out, 0, flags);
        gemm_u<2, 0><<<dim3(4, 8, 16), 256, 0, stream>>>(P0f, Vt, o2d,
            2048, 2048, 2048, 512, 1024L * 2048, 512L * 2048, 1024L * 512, 1.0f, flags);
    } else if (bigws) {
        // two half-batch passes: P0/P1 halves inside the 67MB diffBF region
        __hip_bfloat16* P0h = diffBF;
        __hip_bfloat16* P1h = diffBF + 16777216L;
        for (int h = 0; h < 2; ++h) {
            int bb = h * 8;
            score_kernel<<<dim3(16, 8, 8), 256, 0, stream>>>(Qb, Kb, maskI, lst,
                P0h, P1h, bb);
            finalize_kernel<<<8192, 256, 0, stream>>>(P0h, P1h, lst, lamp,
                d_out, bb, flags);
            gemm_u<2, 0><<<dim3(4, 8, 8), 256, 0, stream>>>(P0h,
                Vt + (long)bb * 512 * 2048, o2d + (long)bb * 1024 * 512,
                2048, 2048, 2048, 512, 1024L * 2048, 512L * 2048, 1024L * 512, 1.0f, flags);
        }
    } else {
        // fallback: bf16 P0 scratch = d_out out0 region, P1 = aliased scratch
        __hip_bfloat16* scratch = (__hip_bfloat16*)d_out;
        for (int h = 0; h < 2; ++h) {
            int bb = h * 8;
            score_kernel<<<dim3(16, 8, 8), 256, 0, stream>>>(Qb, Kb, maskI, lst,
                scratch, P1s, bb);
            finalize_kernel<<<8192, 256, 0, stream>>>(scratch, P1s, lst, lamp,
                d_out, bb, flags);
            gemm_u<2, 0><<<dim3(4, 8, 8), 256, 0, stream>>>(scratch,
                Vt + (long)bb * 512 * 2048, o2d + (long)bb * 1024 * 512,
                2048, 2048, 2048, 512, 1024L * 2048, 512L * 2048, 1024L * 512, 1.0f, flags);
        }
    }

    // rms * gamma * 0.8 -> bf16
    rmsnorm_kernel<<<16384, 64, 0, stream>>>(o2d, gammaF, rmsb);

    // out = rms @ Wo -> d_out out0 region (overwrites any scratch)
    gemm_u<3, 0><<<dim3(4, 128, 1), 256, 0, stream>>>(rmsb, WoT, d_out,
        512, 512, 512, 512, 0, 0, 1024L * 512, 1.0f, flags);
}